// Round 1
// baseline (491.719 us; speedup 1.0000x reference)
//
#include <hip/hip_runtime.h>
#include <hip/hip_bf16.h>
#include <math.h>

#define S_LEN 1024
#define BATCH 8
#define NH 8
#define QD 32
#define PD 4
#define EMB 512
#define NPROJ 544
#define LPOS 2047  // 2*S-1

// ---------------------------------------------------------------------------
// Kernel 1: proj = X (8192x512) @ W^T (512x544) + bias, scattered to Q/K/P
// layouts: Q[h][b][s][32], K[h][b][s][32], P[h][b][s][4]
// Tile 64x64, block 256 (16x16 threads, 4x4 per thread), K-step 16.
// ---------------------------------------------------------------------------
__global__ __launch_bounds__(256) void proj_kernel(
    const float* __restrict__ X, const float* __restrict__ W,
    const float* __restrict__ bias,
    float* __restrict__ Q, float* __restrict__ K, float* __restrict__ P)
{
    __shared__ float as[16][68];  // pad 68: 272B rows, 16B-aligned
    __shared__ float bs[16][68];

    const int m0 = blockIdx.x * 64;
    const int n0 = blockIdx.y * 64;
    const int tid = threadIdx.x;
    const int tx = tid & 15;
    const int ty = tid >> 4;

    float c[4][4] = {};

    for (int k0 = 0; k0 < EMB; k0 += 16) {
        __syncthreads();
#pragma unroll
        for (int u = 0; u < 4; ++u) {
            int idx = tid + 256 * u;            // 0..1023
            int mm = idx >> 4, kk = idx & 15;
            as[kk][mm] = X[(size_t)(m0 + mm) * EMB + k0 + kk];
        }
#pragma unroll
        for (int u = 0; u < 4; ++u) {
            int idx = tid + 256 * u;
            int nn = idx >> 4, kk = idx & 15;
            int o = n0 + nn;
            bs[kk][nn] = (o < NPROJ) ? W[(size_t)o * EMB + k0 + kk] : 0.0f;
        }
        __syncthreads();
#pragma unroll
        for (int kk = 0; kk < 16; ++kk) {
            float a[4], bb[4];
#pragma unroll
            for (int p = 0; p < 4; ++p) a[p] = as[kk][ty * 4 + p];
#pragma unroll
            for (int p = 0; p < 4; ++p) bb[p] = bs[kk][tx * 4 + p];
#pragma unroll
            for (int ii = 0; ii < 4; ++ii)
#pragma unroll
                for (int jj = 0; jj < 4; ++jj)
                    c[ii][jj] += a[ii] * bb[jj];
        }
    }

    const int o_base = n0 + tx * 4;  // multiple of 4
    if (o_base < NPROJ) {
        float4 bv = *(const float4*)(bias + o_base);
#pragma unroll
        for (int ii = 0; ii < 4; ++ii) {
            int r = m0 + ty * 4 + ii;     // r = s*B + b
            int s = r >> 3, b = r & 7;
            float4 v;
            v.x = c[ii][0] + bv.x;
            v.y = c[ii][1] + bv.y;
            v.z = c[ii][2] + bv.z;
            v.w = c[ii][3] + bv.w;
            if (o_base < 256) {
                int h = o_base >> 5, d = o_base & 31;
                *(float4*)(Q + (((size_t)(h * BATCH + b)) * S_LEN + s) * QD + d) = v;
            } else if (o_base < 512) {
                int o2 = o_base - 256;
                int h = o2 >> 5, d = o2 & 31;
                *(float4*)(K + (((size_t)(h * BATCH + b)) * S_LEN + s) * QD + d) = v;
            } else {
                int o3 = o_base - 512;   // 0..31, multiple of 4 -> t==0, h=o3/4
                int h = o3 >> 2;
                *(float4*)(P + (((size_t)(h * BATCH + b)) * S_LEN + s) * PD) = v;
            }
        }
    }
}

// ---------------------------------------------------------------------------
// Kernel 2: PE[h][l][t] = sum_d pos_emb[l][d] * Wp[h*4+t][d]
// ---------------------------------------------------------------------------
__global__ __launch_bounds__(256) void pe_kernel(
    const float* __restrict__ pos, const float* __restrict__ Wp,
    float* __restrict__ PE)
{
    int o = blockIdx.x * 256 + threadIdx.x;
    if (o >= LPOS * 32) return;
    int l = o >> 5;
    int ht = o & 31;
    const float4* pr = (const float4*)(pos + (size_t)l * 192);
    const float4* wr = (const float4*)(Wp + (size_t)ht * 192);
    float acc = 0.0f;
#pragma unroll 8
    for (int d = 0; d < 48; ++d) {
        float4 a = pr[d];
        float4 w = wr[d];
        acc += a.x * w.x + a.y * w.y + a.z * w.z + a.w * w.w;
    }
    int h = ht >> 2, t = ht & 3;
    PE[((size_t)h * LPOS + l) * PD + t] = acc;
}

// ---------------------------------------------------------------------------
// Kernel 3: fused scores + rel-shift pos scores + mask + softmax.
// Grid (S/16, H*B); block 256. Each block: 16 rows i of one (h,b).
// Thread (i_loc=tid/16, sub=tid%16) holds 64 scores: j = sub + 16*m.
// ---------------------------------------------------------------------------
__global__ __launch_bounds__(256) void attn_kernel(
    const float* __restrict__ Q, const float* __restrict__ K,
    const float* __restrict__ P, const float* __restrict__ PE,
    const unsigned char* __restrict__ mask, float* __restrict__ out)
{
    __shared__ float ks[128][36];    // padded K rows, 16B-aligned
    __shared__ float4 pw[1040];      // PE window
    __shared__ float madd[S_LEN];    // 0 or -inf per j

    const int hb = blockIdx.y;
    const int h = hb >> 3;
    const int b = hb & 7;
    const int i0 = blockIdx.x * 16;
    const int tid = threadIdx.x;
    const int i_loc = tid >> 4;
    const int sub = tid & 15;
    const int i = i0 + i_loc;

    // q row into registers (16 threads share a row -> broadcast via L1)
    float q[QD];
    {
        const float4* qrow = (const float4*)(Q + ((size_t)hb * S_LEN + i) * QD);
#pragma unroll
        for (int d = 0; d < 8; ++d) {
            float4 v = qrow[d];
            q[4 * d + 0] = v.x; q[4 * d + 1] = v.y;
            q[4 * d + 2] = v.z; q[4 * d + 3] = v.w;
        }
    }
    float4 pv = *(const float4*)(P + ((size_t)hb * S_LEN + i) * PD);

    // stage PE window: l in [l_min, l_min+1039], pos idx = j + 15 - i_loc
    const int l_min = (S_LEN - 16) - i0;   // = S-1 - (i0+15)
    const float4* peh = (const float4*)(PE + (size_t)h * LPOS * PD);
    for (int idx = tid; idx < 1040; idx += 256) {
        int l = l_min + idx;
        pw[idx] = (l >= 0 && l < LPOS) ? peh[l] : make_float4(0, 0, 0, 0);
    }
    // mask addend
    for (int j = tid; j < S_LEN; j += 256)
        madd[j] = mask[b * S_LEN + j] ? -INFINITY : 0.0f;

    float sc[64];

#pragma unroll
    for (int c = 0; c < 8; ++c) {
        __syncthreads();   // previous chunk consumed (also fences pw/madd for c==0)
        const float* kbase = K + ((size_t)hb * S_LEN + c * 128) * QD;
#pragma unroll
        for (int u = 0; u < 16; ++u) {
            int idx = tid + 256 * u;           // 0..4095
            int r = idx >> 5, col = idx & 31;
            ks[r][col] = kbase[idx];
        }
        __syncthreads();
#pragma unroll
        for (int mm = 0; mm < 8; ++mm) {
            const int m = c * 8 + mm;
            const int j = sub + 16 * m;
            const int jj = sub + 16 * mm;      // row within chunk
            const float4* krow = (const float4*)&ks[jj][0];
            float acc = 0.0f;
#pragma unroll
            for (int d = 0; d < 8; ++d) {
                float4 kv = krow[d];
                acc += q[4 * d + 0] * kv.x + q[4 * d + 1] * kv.y +
                       q[4 * d + 2] * kv.z + q[4 * d + 3] * kv.w;
            }
            float4 pe4 = pw[j + 15 - i_loc];
            acc += pv.x * pe4.x + pv.y * pe4.y + pv.z * pe4.z + pv.w * pe4.w;
            sc[m] = acc + madd[j];
        }
    }

    // row softmax across 16 lanes (sub) holding strided j
    float mx = -INFINITY;
#pragma unroll
    for (int m = 0; m < 64; ++m) mx = fmaxf(mx, sc[m]);
#pragma unroll
    for (int off = 1; off < 16; off <<= 1)
        mx = fmaxf(mx, __shfl_xor(mx, off, 16));

    float sum = 0.0f;
#pragma unroll
    for (int m = 0; m < 64; ++m) {
        sc[m] = __expf(sc[m] - mx);
        sum += sc[m];
    }
#pragma unroll
    for (int off = 1; off < 16; off <<= 1)
        sum += __shfl_xor(sum, off, 16);
    const float inv = 1.0f / sum;

    float* orow = out + ((size_t)hb * S_LEN + i) * S_LEN;
#pragma unroll
    for (int m = 0; m < 64; ++m)
        orow[sub + 16 * m] = sc[m] * inv;
}

// ---------------------------------------------------------------------------
extern "C" void kernel_launch(void* const* d_in, const int* in_sizes, int n_in,
                              void* d_out, int out_size, void* d_ws, size_t ws_size,
                              hipStream_t stream) {
    (void)in_sizes; (void)n_in; (void)out_size; (void)ws_size;
    const float* x           = (const float*)d_in[0];
    const float* pos_emb     = (const float*)d_in[1];
    const unsigned char* msk = (const unsigned char*)d_in[2];
    const float* in_proj_w   = (const float*)d_in[3];
    const float* in_proj_b   = (const float*)d_in[4];
    const float* linear_posw = (const float*)d_in[5];
    float* out = (float*)d_out;

    float* ws = (float*)d_ws;
    float* Q  = ws;                       // H*B*S*32 = 2,097,152 floats
    float* K  = Q + 2097152;              // 2,097,152 floats
    float* P  = K + 2097152;              // H*B*S*4  =   262,144 floats
    float* PE = P + 262144;               // H*LPOS*4 =    65,504 floats
    // total ~18.1 MB of workspace

    proj_kernel<<<dim3(128, 9), 256, 0, stream>>>(x, in_proj_w, in_proj_b, Q, K, P);
    pe_kernel<<<dim3(256), 256, 0, stream>>>(pos_emb, linear_posw, PE);
    attn_kernel<<<dim3(64, 64), 256, 0, stream>>>(Q, K, P, PE, msk, out);
}

// Round 2
// 361.062 us; speedup vs baseline: 1.3619x; 1.3619x over previous
//
#include <hip/hip_runtime.h>
#include <math.h>

#define S_LEN 1024
#define BATCH 8
#define NH 8
#define QD 32
#define PD 4
#define EMB 512
#define NPROJ 544
#define LPOS 2047  // 2*S-1

typedef __attribute__((ext_vector_type(8))) short short8;   // 8 bf16 = 4 VGPR
typedef __attribute__((ext_vector_type(4))) float f32x4;
typedef __attribute__((ext_vector_type(4))) unsigned int u32x4;
typedef __attribute__((ext_vector_type(2))) unsigned int u32x2;

union U4 { u32x4 u; short8 s; };

// fp32 -> bf16 round-to-nearest-even
static __device__ inline unsigned short f2bf(float f) {
    unsigned int u = __builtin_bit_cast(unsigned int, f);
    u += 0x7fffu + ((u >> 16) & 1u);
    return (unsigned short)(u >> 16);
}

// ---------------------------------------------------------------------------
// Kernel 0: convert X (4,194,304 f32) and W (278,528 f32) to bf16.
// ---------------------------------------------------------------------------
#define NXV 1048576   // X float4 count
#define NWV 69632     // W float4 count
__global__ __launch_bounds__(256) void convert_kernel(
    const float* __restrict__ X, const float* __restrict__ W,
    unsigned short* __restrict__ Xb, unsigned short* __restrict__ Wb)
{
    int idx = blockIdx.x * 256 + threadIdx.x;
    const f32x4* src;
    unsigned short* dst;
    int i;
    if (idx < NXV)            { src = (const f32x4*)X; dst = Xb; i = idx; }
    else if (idx < NXV + NWV) { src = (const f32x4*)W; dst = Wb; i = idx - NXV; }
    else return;
    f32x4 v = src[i];
    union { unsigned short s[4]; u32x2 u; } pk;
    pk.s[0] = f2bf(v.x); pk.s[1] = f2bf(v.y);
    pk.s[2] = f2bf(v.z); pk.s[3] = f2bf(v.w);
    ((u32x2*)dst)[i] = pk.u;
}

// ---------------------------------------------------------------------------
// Kernel 1: proj^T = W(544x512) @ X^T(512x8192) via MFMA, scatter to bf16
// Q[h*8+b][s][32], K[h*8+b][s][32], P[h*8+b][s][4].
// Block 256 (4 waves): tile 64 o x 64 m; wave w: 16 m-rows, 4 o-subtiles.
// ---------------------------------------------------------------------------
__global__ __launch_bounds__(256) void proj_kernel(
    const unsigned short* __restrict__ Xb, const unsigned short* __restrict__ Wb,
    const float* __restrict__ bias,
    unsigned short* __restrict__ Qb, unsigned short* __restrict__ Kb,
    unsigned short* __restrict__ Pb)
{
    const int tid = threadIdx.x;
    const int wv = tid >> 6, lane = tid & 63;
    const int n16 = lane & 15, quad = lane >> 4;
    const int m0 = blockIdx.x * 64, o0 = blockIdx.y * 64;
    const int m = m0 + wv * 16 + n16;

    f32x4 acc[4] = {{0,0,0,0},{0,0,0,0},{0,0,0,0},{0,0,0,0}};
    const unsigned short* xrow = Xb + (size_t)m * EMB;

#pragma unroll 4
    for (int k0 = 0; k0 < EMB; k0 += 32) {
        U4 bx; bx.u = *(const u32x4*)(xrow + k0 + quad * 8);
#pragma unroll
        for (int ot = 0; ot < 4; ++ot) {
            int o = o0 + ot * 16 + n16;
            int oc = o < NPROJ ? o : NPROJ - 1;
            U4 aw; aw.u = *(const u32x4*)(Wb + (size_t)oc * EMB + k0 + quad * 8);
            acc[ot] = __builtin_amdgcn_mfma_f32_16x16x32_bf16(aw.s, bx.s, acc[ot], 0, 0, 0);
        }
    }

    const int s = m >> 3, b = m & 7;
#pragma unroll
    for (int ot = 0; ot < 4; ++ot) {
        int obase = o0 + ot * 16 + quad * 4;   // 4 consecutive o per lane
        if (obase >= NPROJ) continue;
        f32x4 bv = *(const f32x4*)(bias + obase);
        union { unsigned short sh[4]; u32x2 u; } pk;
        pk.sh[0] = f2bf(acc[ot].x + bv.x);
        pk.sh[1] = f2bf(acc[ot].y + bv.y);
        pk.sh[2] = f2bf(acc[ot].z + bv.z);
        pk.sh[3] = f2bf(acc[ot].w + bv.w);
        unsigned short* dst;
        if (obase < 256) {
            int h = obase >> 5, d = obase & 31;
            dst = Qb + (((size_t)(h * BATCH + b)) * S_LEN + s) * QD + d;
        } else if (obase < 512) {
            int o2 = obase - 256;
            int h = o2 >> 5, d = o2 & 31;
            dst = Kb + (((size_t)(h * BATCH + b)) * S_LEN + s) * QD + d;
        } else {
            int h = (obase - 512) >> 2;
            dst = Pb + (((size_t)(h * BATCH + b)) * S_LEN + s) * PD;
        }
        *(u32x2*)dst = pk.u;
    }
}

// ---------------------------------------------------------------------------
// Kernel 2: PE[l][ht] = dot(pos[l], Wp[ht]); store REVERSED bf16:
// PEr[h][w][t] = bf16(PE[2046-w][h*4+t])
// ---------------------------------------------------------------------------
__global__ __launch_bounds__(256) void pe_kernel(
    const float* __restrict__ pos, const float* __restrict__ Wp,
    unsigned short* __restrict__ PEr)
{
    int o = blockIdx.x * 256 + threadIdx.x;
    if (o >= LPOS * 32) return;
    int l = o >> 5, ht = o & 31;
    const f32x4* pr = (const f32x4*)(pos + (size_t)l * 192);
    const f32x4* wr = (const f32x4*)(Wp + (size_t)ht * 192);
    float acc = 0.0f;
#pragma unroll 8
    for (int d = 0; d < 48; ++d) {
        f32x4 a = pr[d], w = wr[d];
        acc += a.x * w.x + a.y * w.y + a.z * w.z + a.w * w.w;
    }
    int h = ht >> 2, t = ht & 3, w = 2046 - l;
    PEr[((size_t)h * LPOS + w) * PD + t] = f2bf(acc);
}

// ---------------------------------------------------------------------------
// Kernel 3: scores^T via MFMA + Toeplitz pos-fold + mask + softmax + write.
// Grid (S/16, H*B). Block 256 = 4 waves; wave w covers j in [w*256, w*256+256).
// C^T tile: lane holds row i = i0 + (lane&15), cols j0+quad*4+{0..3}.
// ---------------------------------------------------------------------------
__global__ __launch_bounds__(256) void attn_kernel(
    const unsigned short* __restrict__ Qb, const unsigned short* __restrict__ Kb,
    const unsigned short* __restrict__ Pb, const u32x2* __restrict__ PEr,
    const unsigned char* __restrict__ mask, float* __restrict__ out)
{
    __shared__ u32x2 pe_w[1040];        // reversed PE window (PE4 bf16 per slot)
    __shared__ float madd[S_LEN];
    __shared__ float redm[4][16];
    __shared__ float reds[4][16];

    const int hb = blockIdx.y;
    const int h = hb >> 3, b = hb & 7;
    const int i0 = blockIdx.x * 16;
    const int tid = threadIdx.x;
    const int wv = tid >> 6, lane = tid & 63;
    const int n16 = lane & 15, quad = lane >> 4;

    // stage reversed-PE window: pe_w[w] = PE4[2046 - i0 - w]
    const u32x2* src = PEr + (size_t)h * LPOS + i0;
    for (int wl = tid; wl < 1039; wl += 256) pe_w[wl] = src[wl];
    for (int j = tid; j < S_LEN; j += 256)
        madd[j] = mask[b * S_LEN + j] ? -INFINITY : 0.0f;

    // B1: Q fragment (row i0+n16, k = quad*8..+7)
    U4 b1; b1.u = *(const u32x4*)(Qb + ((size_t)hb * S_LEN + i0 + n16) * QD + quad * 8);
    // P row -> sparse B-frags for the two pos MFMAs
    u32x2 p4 = *(const u32x2*)(Pb + ((size_t)hb * S_LEN + i0 + n16) * PD);
    U4 b2, b3;
    b2.u.x = (n16 == 2 * quad)     ? p4.x : 0u;
    b2.u.y = (n16 == 2 * quad)     ? p4.y : 0u;
    b2.u.z = (n16 == 2 * quad + 1) ? p4.x : 0u;
    b2.u.w = (n16 == 2 * quad + 1) ? p4.y : 0u;
    b3.u.x = (n16 == 2 * quad + 8) ? p4.x : 0u;
    b3.u.y = (n16 == 2 * quad + 8) ? p4.y : 0u;
    b3.u.z = (n16 == 2 * quad + 9) ? p4.x : 0u;
    b3.u.w = (n16 == 2 * quad + 9) ? p4.y : 0u;

    __syncthreads();

    f32x4 sc[16];
    const unsigned short* kbase = Kb + (size_t)hb * S_LEN * QD;

#pragma unroll
    for (int t = 0; t < 16; ++t) {
        const int j0 = wv * 256 + t * 16;
        U4 a1; a1.u = *(const u32x4*)(kbase + (j0 + n16) * QD + quad * 8);
        const int w = 1023 - j0 - n16 + 2 * quad;
        u32x2 e0 = pe_w[w], e1 = pe_w[w + 1];
        u32x2 e8 = pe_w[w + 8], e9 = pe_w[w + 9];
        U4 a2; a2.u.x = e0.x; a2.u.y = e0.y; a2.u.z = e1.x; a2.u.w = e1.y;
        U4 a3; a3.u.x = e8.x; a3.u.y = e8.y; a3.u.z = e9.x; a3.u.w = e9.y;
        f32x4 acc = {0.0f, 0.0f, 0.0f, 0.0f};
        acc = __builtin_amdgcn_mfma_f32_16x16x32_bf16(a3.s, b3.s, acc, 0, 0, 0);
        acc = __builtin_amdgcn_mfma_f32_16x16x32_bf16(a2.s, b2.s, acc, 0, 0, 0);
        acc = __builtin_amdgcn_mfma_f32_16x16x32_bf16(a1.s, b1.s, acc, 0, 0, 0);
        f32x4 mv = *(const f32x4*)&madd[j0 + quad * 4];
        sc[t] = acc + mv;
    }

    // softmax over j for row i = i0 + n16 (lane holds only this row)
    float mx = -INFINITY;
#pragma unroll
    for (int t = 0; t < 16; ++t) {
        mx = fmaxf(mx, fmaxf(fmaxf(sc[t].x, sc[t].y), fmaxf(sc[t].z, sc[t].w)));
    }
    mx = fmaxf(mx, __shfl_xor(mx, 16));
    mx = fmaxf(mx, __shfl_xor(mx, 32));
    if (quad == 0) redm[wv][n16] = mx;
    __syncthreads();
    mx = fmaxf(fmaxf(redm[0][n16], redm[1][n16]),
               fmaxf(redm[2][n16], redm[3][n16]));

    float sum = 0.0f;
#pragma unroll
    for (int t = 0; t < 16; ++t) {
        sc[t].x = __expf(sc[t].x - mx);
        sc[t].y = __expf(sc[t].y - mx);
        sc[t].z = __expf(sc[t].z - mx);
        sc[t].w = __expf(sc[t].w - mx);
        sum += sc[t].x + sc[t].y + sc[t].z + sc[t].w;
    }
    sum += __shfl_xor(sum, 16);
    sum += __shfl_xor(sum, 32);
    if (quad == 0) reds[wv][n16] = sum;
    __syncthreads();
    const float tot = reds[0][n16] + reds[1][n16] + reds[2][n16] + reds[3][n16];
    const float inv = 1.0f / tot;

    float* orow = out + ((size_t)hb * S_LEN + i0 + n16) * S_LEN;
#pragma unroll
    for (int t = 0; t < 16; ++t) {
        const int j0 = wv * 256 + t * 16 + quad * 4;
        f32x4 o4 = sc[t] * inv;
        *(f32x4*)(orow + j0) = o4;
    }
}

// ---------------------------------------------------------------------------
extern "C" void kernel_launch(void* const* d_in, const int* in_sizes, int n_in,
                              void* d_out, int out_size, void* d_ws, size_t ws_size,
                              hipStream_t stream) {
    (void)in_sizes; (void)n_in; (void)out_size; (void)ws_size;
    const float* x           = (const float*)d_in[0];
    const float* pos_emb     = (const float*)d_in[1];
    const unsigned char* msk = (const unsigned char*)d_in[2];
    const float* in_proj_w   = (const float*)d_in[3];
    const float* in_proj_b   = (const float*)d_in[4];
    const float* linear_posw = (const float*)d_in[5];
    float* out = (float*)d_out;

    char* p = (char*)d_ws;
    unsigned short* Qb  = (unsigned short*)p; p += (size_t)4 << 20;  // 4 MB
    unsigned short* Kb  = (unsigned short*)p; p += (size_t)4 << 20;  // 4 MB
    unsigned short* Pb  = (unsigned short*)p; p += 524288;           // 0.5 MB
    unsigned short* PEr = (unsigned short*)p; p += 131072;           // 128 KB
    unsigned short* Xb  = (unsigned short*)p; p += (size_t)8 << 20;  // 8 MB
    unsigned short* Wb  = (unsigned short*)p; p += 557056;           // ~0.53 MB
    // total ~17.2 MB (round-1 used 18.1 MB successfully)

    convert_kernel<<<4368, 256, 0, stream>>>(x, in_proj_w, Xb, Wb);
    pe_kernel<<<256, 256, 0, stream>>>(pos_emb, linear_posw, PEr);
    proj_kernel<<<dim3(128, 9), 256, 0, stream>>>(Xb, Wb, in_proj_b, Qb, Kb, Pb);
    attn_kernel<<<dim3(64, 64), 256, 0, stream>>>(Qb, Kb, Pb, (const u32x2*)PEr, msk, out);
}

// Round 3
// 352.404 us; speedup vs baseline: 1.3953x; 1.0246x over previous
//
#include <hip/hip_runtime.h>
#include <math.h>

#define S_LEN 1024
#define BATCH 8
#define NH 8
#define QD 32
#define PD 4
#define EMB 512
#define NPROJ 544
#define LPOS 2047  // 2*S-1

typedef __attribute__((ext_vector_type(8))) short short8;   // 8 bf16 = 4 VGPR
typedef __attribute__((ext_vector_type(4))) float f32x4;
typedef __attribute__((ext_vector_type(4))) unsigned int u32x4;
typedef __attribute__((ext_vector_type(2))) unsigned int u32x2;

union U4 { u32x4 u; short8 s; };

// fp32 -> bf16 round-to-nearest-even
static __device__ inline unsigned short f2bf(float f) {
    unsigned int u = __builtin_bit_cast(unsigned int, f);
    u += 0x7fffu + ((u >> 16) & 1u);
    return (unsigned short)(u >> 16);
}

// ---------------------------------------------------------------------------
// Kernel 0: convert X (4,194,304 f32) and W (278,528 f32) to bf16.
// ---------------------------------------------------------------------------
#define NXV 1048576   // X float4 count
#define NWV 69632     // W float4 count
__global__ __launch_bounds__(256) void convert_kernel(
    const float* __restrict__ X, const float* __restrict__ W,
    unsigned short* __restrict__ Xb, unsigned short* __restrict__ Wb)
{
    int idx = blockIdx.x * 256 + threadIdx.x;
    const f32x4* src;
    unsigned short* dst;
    int i;
    if (idx < NXV)            { src = (const f32x4*)X; dst = Xb; i = idx; }
    else if (idx < NXV + NWV) { src = (const f32x4*)W; dst = Wb; i = idx - NXV; }
    else return;
    f32x4 v = src[i];
    union { unsigned short s[4]; u32x2 u; } pk;
    pk.s[0] = f2bf(v.x); pk.s[1] = f2bf(v.y);
    pk.s[2] = f2bf(v.z); pk.s[3] = f2bf(v.w);
    ((u32x2*)dst)[i] = pk.u;
}

// ---------------------------------------------------------------------------
// Kernel 1: proj^T = W(544x512) @ X^T(512x8192) via MFMA.
// W o-tile staged in LDS (2 k-phases of 256), conflict-free padded rows.
// Block 256 (4 waves): tile 64 o x 64 m; wave wv: 16 m-rows, 4 o-subtiles.
// ---------------------------------------------------------------------------
#define WROW 264   // shorts per LDS W row (256 data + 8 pad): 528 B, 16B-aligned,
                   // row step 132 words -> +4 banks/row -> 2-way on b128 (free)
__global__ __launch_bounds__(256) void proj_kernel(
    const unsigned short* __restrict__ Xb, const unsigned short* __restrict__ Wb,
    const float* __restrict__ bias,
    unsigned short* __restrict__ Qb, unsigned short* __restrict__ Kb,
    unsigned short* __restrict__ Pb)
{
    __shared__ unsigned short wlds[64 * WROW];   // 33,792 B

    const int tid = threadIdx.x;
    const int wv = tid >> 6, lane = tid & 63;
    const int n16 = lane & 15, quad = lane >> 4;
    const int m0 = blockIdx.x * 64, o0 = blockIdx.y * 64;
    const int m = m0 + wv * 16 + n16;
    const unsigned short* xrow = Xb + (size_t)m * EMB;

    f32x4 acc[4] = {{0,0,0,0},{0,0,0,0},{0,0,0,0},{0,0,0,0}};

#pragma unroll
    for (int phase = 0; phase < 2; ++phase) {
        __syncthreads();   // previous phase fully consumed
#pragma unroll
        for (int u = 0; u < 8; ++u) {
            int idx = tid + 256 * u;          // 0..2047
            int r = idx >> 5, c = idx & 31;   // row, 16B chunk within 512B half-row
            int o = o0 + r; if (o > NPROJ - 1) o = NPROJ - 1;
            u32x4 v = *(const u32x4*)(Wb + (size_t)o * EMB + phase * 256 + c * 8);
            *(u32x4*)(wlds + r * WROW + c * 8) = v;
        }
        __syncthreads();
#pragma unroll
        for (int kk = 0; kk < 8; ++kk) {
            const int k0 = kk * 32;
            U4 bx; bx.u = *(const u32x4*)(xrow + phase * 256 + k0 + quad * 8);
#pragma unroll
            for (int ot = 0; ot < 4; ++ot) {
                U4 aw; aw.u = *(const u32x4*)(wlds + (ot * 16 + n16) * WROW + k0 + quad * 8);
                acc[ot] = __builtin_amdgcn_mfma_f32_16x16x32_bf16(aw.s, bx.s, acc[ot], 0, 0, 0);
            }
        }
    }

    const int s = m >> 3, b = m & 7;
#pragma unroll
    for (int ot = 0; ot < 4; ++ot) {
        int obase = o0 + ot * 16 + quad * 4;   // 4 consecutive o per lane
        if (obase >= NPROJ) continue;
        f32x4 bv = *(const f32x4*)(bias + obase);
        union { unsigned short sh[4]; u32x2 u; } pk;
        pk.sh[0] = f2bf(acc[ot].x + bv.x);
        pk.sh[1] = f2bf(acc[ot].y + bv.y);
        pk.sh[2] = f2bf(acc[ot].z + bv.z);
        pk.sh[3] = f2bf(acc[ot].w + bv.w);
        unsigned short* dst;
        if (obase < 256) {
            int h = obase >> 5, d = obase & 31;
            dst = Qb + (((size_t)(h * BATCH + b)) * S_LEN + s) * QD + d;
        } else if (obase < 512) {
            int o2 = obase - 256;
            int h = o2 >> 5, d = o2 & 31;
            dst = Kb + (((size_t)(h * BATCH + b)) * S_LEN + s) * QD + d;
        } else {
            int h = (obase - 512) >> 2;
            dst = Pb + (((size_t)(h * BATCH + b)) * S_LEN + s) * PD;
        }
        *(u32x2*)dst = pk.u;
    }
}

// ---------------------------------------------------------------------------
// Kernel 2: PE[l][ht] = dot(pos[l], Wp[ht]); store REVERSED bf16:
// PEr[h][w][t] = bf16(PE[2046-w][h*4+t])
// ---------------------------------------------------------------------------
__global__ __launch_bounds__(256) void pe_kernel(
    const float* __restrict__ pos, const float* __restrict__ Wp,
    unsigned short* __restrict__ PEr)
{
    int o = blockIdx.x * 256 + threadIdx.x;
    if (o >= LPOS * 32) return;
    int l = o >> 5, ht = o & 31;
    const f32x4* pr = (const f32x4*)(pos + (size_t)l * 192);
    const f32x4* wr = (const f32x4*)(Wp + (size_t)ht * 192);
    float acc = 0.0f;
#pragma unroll 8
    for (int d = 0; d < 48; ++d) {
        f32x4 a = pr[d], w = wr[d];
        acc += a.x * w.x + a.y * w.y + a.z * w.z + a.w * w.w;
    }
    int h = ht >> 2, t = ht & 3, w = 2046 - l;
    PEr[((size_t)h * LPOS + w) * PD + t] = f2bf(acc);
}

// ---------------------------------------------------------------------------
// Kernel 3: scores^T via MFMA + Toeplitz pos-fold + mask + softmax + write.
// Grid (S/16, H*B). Block 256 = 4 waves; wave wv covers j in [wv*256, +256).
// C^T tile: lane holds row i = i0 + (lane&15), cols j0+quad*4+{0..3}.
// PE window staged as PAIRS so each pos A-frag is one aligned ds_read_b128.
// ---------------------------------------------------------------------------
__global__ __launch_bounds__(256, 3) void attn_kernel(
    const unsigned short* __restrict__ Qb, const unsigned short* __restrict__ Kb,
    const unsigned short* __restrict__ Pb, const u32x2* __restrict__ PEr,
    const unsigned char* __restrict__ mask, float* __restrict__ out)
{
    __shared__ u32x4 pe_pair[1040];     // {PE4[w], PE4[w+1]} bf16, 16 B/slot
    __shared__ float madd[S_LEN];
    __shared__ float redm[4][16];
    __shared__ float reds[4][16];

    const int hb = blockIdx.y;
    const int h = hb >> 3, b = hb & 7;
    const int i0 = blockIdx.x * 16;
    const int tid = threadIdx.x;
    const int wv = tid >> 6, lane = tid & 63;
    const int n16 = lane & 15, quad = lane >> 4;

    // stage reversed-PE pair window: pe_pair[w] = {PE4r[i0+w], PE4r[i0+w+1]}
    const u32x2* src = PEr + (size_t)h * LPOS + i0;
    for (int wl = tid; wl < 1039; wl += 256) {
        u32x2 lo = src[wl];
        u32x2 hi = (i0 + wl + 1 <= LPOS - 1) ? src[wl + 1] : lo;  // clamp (unused slot)
        u32x4 v; v.x = lo.x; v.y = lo.y; v.z = hi.x; v.w = hi.y;
        pe_pair[wl] = v;
    }
    for (int j = tid; j < S_LEN; j += 256)
        madd[j] = mask[b * S_LEN + j] ? -INFINITY : 0.0f;

    // B1: Q fragment (row i0+n16, k = quad*8..+7)
    U4 b1; b1.u = *(const u32x4*)(Qb + ((size_t)hb * S_LEN + i0 + n16) * QD + quad * 8);
    // P row -> sparse B-frags for the two pos MFMAs
    u32x2 p4 = *(const u32x2*)(Pb + ((size_t)hb * S_LEN + i0 + n16) * PD);
    U4 b2, b3;
    b2.u.x = (n16 == 2 * quad)     ? p4.x : 0u;
    b2.u.y = (n16 == 2 * quad)     ? p4.y : 0u;
    b2.u.z = (n16 == 2 * quad + 1) ? p4.x : 0u;
    b2.u.w = (n16 == 2 * quad + 1) ? p4.y : 0u;
    b3.u.x = (n16 == 2 * quad + 8) ? p4.x : 0u;
    b3.u.y = (n16 == 2 * quad + 8) ? p4.y : 0u;
    b3.u.z = (n16 == 2 * quad + 9) ? p4.x : 0u;
    b3.u.w = (n16 == 2 * quad + 9) ? p4.y : 0u;

    __syncthreads();

    f32x4 sc[16];
    const unsigned short* kbase =
        Kb + (size_t)hb * S_LEN * QD + (size_t)(wv * 256 + n16) * QD + quad * 8;
    const int wbase = 1023 - wv * 256 - n16 + 2 * quad;

#pragma unroll
    for (int t = 0; t < 16; ++t) {
        U4 a1; a1.u = *(const u32x4*)(kbase + t * 16 * QD);
        U4 a2; a2.u = pe_pair[wbase - t * 16];
        U4 a3; a3.u = pe_pair[wbase - t * 16 + 8];
        f32x4 acc = {0.0f, 0.0f, 0.0f, 0.0f};
        acc = __builtin_amdgcn_mfma_f32_16x16x32_bf16(a3.s, b3.s, acc, 0, 0, 0);
        acc = __builtin_amdgcn_mfma_f32_16x16x32_bf16(a2.s, b2.s, acc, 0, 0, 0);
        acc = __builtin_amdgcn_mfma_f32_16x16x32_bf16(a1.s, b1.s, acc, 0, 0, 0);
        sc[t] = acc + *(const f32x4*)&madd[wv * 256 + t * 16 + quad * 4];
    }

    // softmax over j for row i = i0 + n16 (lane holds only this row)
    float mx = -INFINITY;
#pragma unroll
    for (int t = 0; t < 16; ++t)
        mx = fmaxf(mx, fmaxf(fmaxf(sc[t].x, sc[t].y), fmaxf(sc[t].z, sc[t].w)));
    mx = fmaxf(mx, __shfl_xor(mx, 16));
    mx = fmaxf(mx, __shfl_xor(mx, 32));
    if (quad == 0) redm[wv][n16] = mx;
    __syncthreads();
    mx = fmaxf(fmaxf(redm[0][n16], redm[1][n16]),
               fmaxf(redm[2][n16], redm[3][n16]));

    float sum = 0.0f;
#pragma unroll
    for (int t = 0; t < 16; ++t) {
        sc[t].x = __expf(sc[t].x - mx);
        sc[t].y = __expf(sc[t].y - mx);
        sc[t].z = __expf(sc[t].z - mx);
        sc[t].w = __expf(sc[t].w - mx);
        sum += sc[t].x + sc[t].y + sc[t].z + sc[t].w;
    }
    sum += __shfl_xor(sum, 16);
    sum += __shfl_xor(sum, 32);
    if (quad == 0) reds[wv][n16] = sum;
    __syncthreads();
    const float tot = reds[0][n16] + reds[1][n16] + reds[2][n16] + reds[3][n16];
    const float inv = 1.0f / tot;

    float* orow = out + ((size_t)hb * S_LEN + i0 + n16) * S_LEN;
#pragma unroll
    for (int t = 0; t < 16; ++t) {
        const int j0 = wv * 256 + t * 16 + quad * 4;
        f32x4 o4 = sc[t] * inv;
        __builtin_nontemporal_store(o4, (f32x4*)(orow + j0));
    }
}

// ---------------------------------------------------------------------------
extern "C" void kernel_launch(void* const* d_in, const int* in_sizes, int n_in,
                              void* d_out, int out_size, void* d_ws, size_t ws_size,
                              hipStream_t stream) {
    (void)in_sizes; (void)n_in; (void)out_size; (void)ws_size;
    const float* x           = (const float*)d_in[0];
    const float* pos_emb     = (const float*)d_in[1];
    const unsigned char* msk = (const unsigned char*)d_in[2];
    const float* in_proj_w   = (const float*)d_in[3];
    const float* in_proj_b   = (const float*)d_in[4];
    const float* linear_posw = (const float*)d_in[5];
    float* out = (float*)d_out;

    char* p = (char*)d_ws;
    unsigned short* Qb  = (unsigned short*)p; p += (size_t)4 << 20;  // 4 MB
    unsigned short* Kb  = (unsigned short*)p; p += (size_t)4 << 20;  // 4 MB
    unsigned short* Pb  = (unsigned short*)p; p += 524288;           // 0.5 MB
    unsigned short* PEr = (unsigned short*)p; p += 131072;           // 128 KB
    unsigned short* Xb  = (unsigned short*)p; p += (size_t)8 << 20;  // 8 MB
    unsigned short* Wb  = (unsigned short*)p; p += 557056;           // ~0.53 MB

    convert_kernel<<<4368, 256, 0, stream>>>(x, in_proj_w, Xb, Wb);
    pe_kernel<<<256, 256, 0, stream>>>(pos_emb, linear_posw, PEr);
    proj_kernel<<<dim3(128, 9), 256, 0, stream>>>(Xb, Wb, in_proj_b, Qb, Kb, Pb);
    attn_kernel<<<dim3(64, 64), 256, 0, stream>>>(Qb, Kb, Pb, (const u32x2*)PEr, msk, out);
}